// Round 1
// baseline (292.631 us; speedup 1.0000x reference)
//
#include <hip/hip_runtime.h>
#include <hip/hip_fp16.h>

#define N_PTS 100000
#define KSZ 9
#define C_IN 24
#define C_HID 144
#define C_OUT 24
#define EPSV 1e-5f

// ---- workspace layout (byte offsets) ----
// x1n: fp16 (N+1) x 144   [0, 28,800,288) -> padded region ends 28,800,512
// x2 : fp16  N    x 144   [28,800,512, 57,600,512)
// st : f32 stats          [57,600,512, +4096)
// y3 : f32  N x 24        aliases x1n region (x1n dead after k_conv)
#define X1N_B 0ull
#define X2_B  28800512ull
#define ST_B  57600512ull
#define Y3_B  0ull

// stat offsets in floats (within ST)
#define MU1_F  0     // 24   raw sums of feats
#define M1_F   32    // 576  raw F^T F
#define SUM2_F 640   // 144
#define SQ2_F  800   // 144
#define SUM3_F 960   // 24
#define SQ3_F  992   // 24
#define ST_FLOATS 1024

typedef float f4v __attribute__((ext_vector_type(4)));

__device__ inline float4 f4z() { return make_float4(0.f, 0.f, 0.f, 0.f); }
__device__ inline float4 f4_fma_s(float s, float4 b, float4 c) {
    return make_float4(fmaf(s, b.x, c.x), fmaf(s, b.y, c.y),
                       fmaf(s, b.z, c.z), fmaf(s, b.w, c.w));
}
__device__ inline float clamp6(float x) { return fminf(fmaxf(x, 0.f), 6.f); }

// ---- K0: zero stats + fp16 sentinel row (ws re-poisoned before every call)
__global__ void k_init(char* wsb) {
    int t = threadIdx.x;
    float* STF = (float*)(wsb + ST_B);
    for (int i = t; i < ST_FLOATS; i += 256) STF[i] = 0.f;
    // sentinel row N of x1n: 144 halves = 72 floats of zero bits
    float* sent = (float*)(wsb + X1N_B + (size_t)N_PTS * (C_HID * 2));
    if (t < 72) sent[t] = 0.f;
}

// ---- K1: feats moments straight from global (no LDS tile).
// thread = task: 0..575 -> (i,j) of F^T F ; 576..599 -> mu1 column sum.
// j-read is coalesced within the 96B row; i-read is a same-address broadcast;
// rows stay L1-resident within a block (each block owns a contiguous row slice).
__global__ void k_moments(const float* __restrict__ feats, char* __restrict__ wsb) {
    int t = threadIdx.x;  // blockDim 640, 600 active
    float* STF = (float*)(wsb + ST_B);
    int len = (N_PTS + gridDim.x - 1) / gridDim.x;
    int r0 = blockIdx.x * len;
    int r1 = min(r0 + len, N_PTS);
    if (t >= 600) return;
    float a = 0.f;
    if (t < 576) {
        int i = t / 24, j = t % 24;
#pragma unroll 4
        for (int r = r0; r < r1; r++)
            a = fmaf(feats[(size_t)r * 24 + i], feats[(size_t)r * 24 + j], a);
        atomicAdd(&STF[M1_F + t], a);
    } else {
        int k = t - 576;
#pragma unroll 4
        for (int r = r0; r < r1; r++) a += feats[(size_t)r * 24 + k];
        atomicAdd(&STF[MU1_F + k], a);
    }
}

// ---- K2: GEMM1 (N,24)@(24,144) + BN1 + relu6 -> x1n (fp16).
// Fused fin1 prologue (closed-form BN1 from raw moments, per block, cheap).
// Mapping: c = t%144 (weight column in 24 VGPRs, BN scale folded in),
// pg = t/144 (4 point-groups). Zero LDS in the inner loop; 2B stores coalesce.
__global__ void __launch_bounds__(576, 5)
k_gemm1(const float* __restrict__ feats, const float* __restrict__ w1,
        const float* __restrict__ g1, const float* __restrict__ b1,
        char* __restrict__ wsb) {
    __shared__ float scs[C_HID], shs[C_HID];
    float* STF = (float*)(wsb + ST_B);
    int t = threadIdx.x;
    if (t < C_HID) {
        float wc[C_IN];
#pragma unroll
        for (int k = 0; k < C_IN; k++) wc[k] = w1[k * C_HID + t];
        const float invN = 1.f / (float)N_PTS;
        float mean = 0.f;
#pragma unroll
        for (int k = 0; k < C_IN; k++) mean = fmaf(STF[MU1_F + k], wc[k], mean);
        mean *= invN;
        float e2 = 0.f;
        for (int i = 0; i < C_IN; i++) {
            float s = 0.f;
#pragma unroll
            for (int j = 0; j < C_IN; j++) s = fmaf(STF[M1_F + i * 24 + j], wc[j], s);
            e2 = fmaf(wc[i], s, e2);
        }
        e2 *= invN;
        float var = e2 - mean * mean;
        float s1 = g1[t] * rsqrtf(var + EPSV);
        scs[t] = s1;
        shs[t] = b1[t] - mean * s1;
    }
    __syncthreads();
    int c = t % C_HID, pg = t / C_HID;  // pg in [0,4)
    float sc = scs[c];
    float sh = shs[c];
    float wreg[C_IN];
#pragma unroll
    for (int k = 0; k < C_IN; k++) wreg[k] = w1[k * C_HID + c] * sc;  // fold BN scale
    __half* x1h = (__half*)(wsb + X1N_B);
    for (int p = blockIdx.x * 4 + pg; p < N_PTS; p += gridDim.x * 4) {
        const float4* fr = (const float4*)(feats + (size_t)p * C_IN);
        float acc = sh;
#pragma unroll
        for (int q = 0; q < 6; q++) {
            float4 f = fr[q];
            acc = fmaf(f.x, wreg[4 * q + 0], acc);
            acc = fmaf(f.y, wreg[4 * q + 1], acc);
            acc = fmaf(f.z, wreg[4 * q + 2], acc);
            acc = fmaf(f.w, wreg[4 * q + 3], acc);
        }
        x1h[(size_t)p * C_HID + c] = __float2half_rn(clamp6(acc));
    }
}

// ---- K3: channelwise 3x3 conv (fp16 gather, 18 lanes/row, 8ch/lane)
// + fused BN2 stat accumulation. Prefetches next chunk's in_idx to break the
// idx->gather chain; non-temporal x2 store to keep x1n in L2.
__global__ void k_conv(const float* __restrict__ w2, const int* __restrict__ in_idx,
                       char* __restrict__ wsb) {
    __shared__ float w2s[KSZ * C_HID];
    __shared__ float lsum[C_HID], lsq[C_HID];
    float* STF = (float*)(wsb + ST_B);
    int t = threadIdx.x;
    for (int e = t; e < KSZ * C_HID; e += 256) w2s[e] = w2[e];
    if (t < C_HID) { lsum[t] = 0.f; lsq[t] = 0.f; }
    __syncthreads();
    const __half* x1h = (const __half*)(wsb + X1N_B);
    __half* x2h = (__half*)(wsb + X2_B);
    const bool act = t < 252;           // 14 points x 18 lanes
    int pt = t / 18, g = t % 18, c0 = g * 8;
    float rs[8], rq[8];
#pragma unroll
    for (int j = 0; j < 8; j++) { rs[j] = 0.f; rq[j] = 0.f; }
    const int nChunks = (N_PTS + 13) / 14;
    int ch = (int)blockIdx.x;
    int p = ch * 14 + pt;
    bool ok = act && p < N_PTS;
    int idxs[KSZ];
#pragma unroll
    for (int k = 0; k < KSZ; k++) idxs[k] = ok ? in_idx[k * N_PTS + p] : N_PTS;
    while (ch < nChunks) {
        // issue all 9 gathers (16B = 8 fp16 channels per lane)
        float4 vv[KSZ];
#pragma unroll
        for (int k = 0; k < KSZ; k++)
            vv[k] = *(const float4*)(x1h + (size_t)idxs[k] * C_HID + c0);
        // prefetch next chunk's indices while gathers are in flight
        int chn = ch + (int)gridDim.x;
        int pn = chn * 14 + pt;
        bool okn = act && chn < nChunks && pn < N_PTS;
        int idxn[KSZ];
#pragma unroll
        for (int k = 0; k < KSZ; k++) idxn[k] = okn ? in_idx[k * N_PTS + pn] : N_PTS;
        // compute
        float acc[8];
#pragma unroll
        for (int j = 0; j < 8; j++) acc[j] = 0.f;
#pragma unroll
        for (int k = 0; k < KSZ; k++) {
            union { float4 f; __half2 h[4]; } u;
            u.f = vv[k];
#pragma unroll
            for (int jj = 0; jj < 4; jj++) {
                float2 x = __half22float2(u.h[jj]);
                acc[2 * jj]     = fmaf(w2s[k * C_HID + c0 + 2 * jj],     x.x, acc[2 * jj]);
                acc[2 * jj + 1] = fmaf(w2s[k * C_HID + c0 + 2 * jj + 1], x.y, acc[2 * jj + 1]);
            }
        }
        if (ok) {
            union { f4v f; __half2 h[4]; } o;
#pragma unroll
            for (int jj = 0; jj < 4; jj++)
                o.h[jj] = __float22half2_rn(make_float2(acc[2 * jj], acc[2 * jj + 1]));
            __builtin_nontemporal_store(o.f, (f4v*)(x2h + (size_t)p * C_HID + c0));
#pragma unroll
            for (int j = 0; j < 8; j++) {
                rs[j] += acc[j];
                rq[j] = fmaf(acc[j], acc[j], rq[j]);
            }
        }
        ch = chn; p = pn; ok = okn;
#pragma unroll
        for (int k = 0; k < KSZ; k++) idxs[k] = idxn[k];
    }
    if (act) {
#pragma unroll
        for (int j = 0; j < 8; j++) {
            atomicAdd(&lsum[c0 + j], rs[j]);
            atomicAdd(&lsq[c0 + j], rq[j]);
        }
    }
    __syncthreads();
    if (t < C_HID) {
        atomicAdd(&STF[SUM2_F + t], lsum[t]);
        atomicAdd(&STF[SQ2_F + t], lsq[t]);
    }
}

// ---- K4: GEMM2 (N,144)@(144,24), BN2+relu6 on the fly, fp16 x2 input,
// fused fin2 prologue, 1 row/thread (391 blocks -> 1563 waves).
__global__ void k_gemm2(const float* __restrict__ w3, const float* __restrict__ g2,
                        const float* __restrict__ b2, char* __restrict__ wsb) {
    __shared__ float4 w3s[C_HID * 6];
    __shared__ float4 sc2v[C_HID / 4], sh2v[C_HID / 4];
    float* STF = (float*)(wsb + ST_B);
    int t = threadIdx.x;
    for (int e = t; e < C_HID * 6; e += 256) w3s[e] = ((const float4*)w3)[e];
    if (t < C_HID) {
        const float invN = 1.f / (float)N_PTS;
        float mean = STF[SUM2_F + t] * invN;
        float var = STF[SQ2_F + t] * invN - mean * mean;
        float s = g2[t] * rsqrtf(var + EPSV);
        ((float*)sc2v)[t] = s;
        ((float*)sh2v)[t] = b2[t] - mean * s;
    }
    __syncthreads();
    int r = blockIdx.x * 256 + t;
    if (r >= N_PTS) return;
    const float4* x2v = (const float4*)(wsb + X2_B + (size_t)r * (C_HID * 2));
    float4 a[6];
#pragma unroll
    for (int c4 = 0; c4 < 6; c4++) a[c4] = f4z();
#pragma unroll 6
    for (int h8 = 0; h8 < 18; h8++) {
        union { float4 f; __half2 h[4]; } u;
        u.f = x2v[h8];
        float4 s0 = sc2v[2 * h8], s1 = sc2v[2 * h8 + 1];
        float4 b0 = sh2v[2 * h8], b1 = sh2v[2 * h8 + 1];
        float2 x0 = __half22float2(u.h[0]);
        float2 x1 = __half22float2(u.h[1]);
        float2 x2 = __half22float2(u.h[2]);
        float2 x3 = __half22float2(u.h[3]);
        float xs[8];
        xs[0] = clamp6(fmaf(x0.x, s0.x, b0.x));
        xs[1] = clamp6(fmaf(x0.y, s0.y, b0.y));
        xs[2] = clamp6(fmaf(x1.x, s0.z, b0.z));
        xs[3] = clamp6(fmaf(x1.y, s0.w, b0.w));
        xs[4] = clamp6(fmaf(x2.x, s1.x, b1.x));
        xs[5] = clamp6(fmaf(x2.y, s1.y, b1.y));
        xs[6] = clamp6(fmaf(x3.x, s1.z, b1.z));
        xs[7] = clamp6(fmaf(x3.y, s1.w, b1.w));
#pragma unroll
        for (int j = 0; j < 8; j++) {
            int h = h8 * 8 + j;
#pragma unroll
            for (int c4 = 0; c4 < 6; c4++)
                a[c4] = f4_fma_s(xs[j], w3s[h * 6 + c4], a[c4]);
        }
    }
    float4* y3v = (float4*)(wsb + Y3_B) + (size_t)r * 6;
#pragma unroll
    for (int c4 = 0; c4 < 6; c4++) y3v[c4] = a[c4];
}

// ---- K5: BN3 stats over y3 (channel-stable mapping: blockDim=192, c = t%24)
__global__ void k_red3(char* __restrict__ wsb) {
    int t = threadIdx.x;  // blockDim 192
    const float* y3 = (const float*)(wsb + Y3_B);
    float* STF = (float*)(wsb + ST_B);
    float rs = 0.f, rq = 0.f;
    const int total = N_PTS * C_OUT;
    for (int e = blockIdx.x * 192 + t; e < total; e += gridDim.x * 192) {
        float v = y3[e];
        rs += v;
        rq = fmaf(v, v, rq);
    }
    __shared__ float ls[192], lq[192];
    ls[t] = rs; lq[t] = rq;
    __syncthreads();
    if (t < C_OUT) {
        float s = 0.f, q = 0.f;
        for (int u = t; u < 192; u += C_OUT) { s += ls[u]; q += lq[u]; }
        atomicAdd(&STF[SUM3_F + t], s);
        atomicAdd(&STF[SQ3_F + t], q);
    }
}

// ---- K6: out = bn3(y3) + feats, fused fin3 prologue
__global__ void k_out(const float* __restrict__ feats, const float* __restrict__ g3,
                      const float* __restrict__ b3, const char* __restrict__ wsb,
                      float* __restrict__ out) {
    __shared__ float s3[C_OUT], h3[C_OUT];
    const float* STF = (const float*)(wsb + ST_B);
    int t = threadIdx.x;
    if (t < C_OUT) {
        const float invN = 1.f / (float)N_PTS;
        float mean = STF[SUM3_F + t] * invN;
        float var = STF[SQ3_F + t] * invN - mean * mean;
        float s = g3[t] * rsqrtf(var + EPSV);
        s3[t] = s;
        h3[t] = b3[t] - mean * s;
    }
    __syncthreads();
    int tau = blockIdx.x * 256 + t;
    if (tau >= N_PTS * 6) return;
    int c = (tau % 6) * 4;
    float4 y = ((const float4*)(wsb + Y3_B))[tau];
    float4 f = ((const float4*)feats)[tau];
    float4 o;
    o.x = fmaf(y.x, s3[c + 0], h3[c + 0]) + f.x;
    o.y = fmaf(y.y, s3[c + 1], h3[c + 1]) + f.y;
    o.z = fmaf(y.z, s3[c + 2], h3[c + 2]) + f.z;
    o.w = fmaf(y.w, s3[c + 3], h3[c + 3]) + f.w;
    ((float4*)out)[tau] = o;
}

extern "C" void kernel_launch(void* const* d_in, const int* in_sizes, int n_in,
                              void* d_out, int out_size, void* d_ws, size_t ws_size,
                              hipStream_t stream) {
    const float* feats = (const float*)d_in[0];
    const float* w1 = (const float*)d_in[1];
    const float* g1 = (const float*)d_in[2];
    const float* b1 = (const float*)d_in[3];
    const float* w2 = (const float*)d_in[4];
    const float* g2 = (const float*)d_in[5];
    const float* b2 = (const float*)d_in[6];
    const float* w3 = (const float*)d_in[7];
    const float* g3 = (const float*)d_in[8];
    const float* b3 = (const float*)d_in[9];
    const int* in_idx = (const int*)d_in[10];
    char* wsb = (char*)d_ws;
    float* out = (float*)d_out;

    hipLaunchKernelGGL(k_init, dim3(1), dim3(256), 0, stream, wsb);
    hipLaunchKernelGGL(k_moments, dim3(256), dim3(640), 0, stream, feats, wsb);
    hipLaunchKernelGGL(k_gemm1, dim3(1024), dim3(576), 0, stream, feats, w1, g1, b1, wsb);
    hipLaunchKernelGGL(k_conv, dim3(2048), dim3(256), 0, stream, w2, in_idx, wsb);
    hipLaunchKernelGGL(k_gemm2, dim3((N_PTS + 255) / 256), dim3(256), 0, stream, w3, g2, b2, wsb);
    hipLaunchKernelGGL(k_red3, dim3(512), dim3(192), 0, stream, wsb);
    hipLaunchKernelGGL(k_out, dim3((N_PTS * 6 + 255) / 256), dim3(256), 0, stream,
                       feats, g3, b3, wsb, out);
}